// Round 7
// baseline (1299.645 us; speedup 1.0000x reference)
//
#include <hip/hip_runtime.h>
#include <stdint.h>

// FlashbackPlusPlus: embed->GRU->spatiotemporal causal attention->FC
// S=256 U=64 H=256 V=10000
#define S_LEN 256
#define U_LEN 64
#define H_DIM 256
#define V_DIM 10000
#define Y_ELEMS 163840000LL  // S*U*V

typedef short bf16x8 __attribute__((ext_vector_type(8)));
typedef float f32x4 __attribute__((ext_vector_type(4)));

__device__ __forceinline__ short f2bf(float f) {
  union { float f; uint32_t u; } v; v.f = f;
  uint32_t r = v.u + 0x7FFFu + ((v.u >> 16) & 1u);  // RNE
  return (short)(r >> 16);
}
__device__ __forceinline__ float bf2f(short s) {
  union { uint32_t u; float f; } v; v.u = ((uint32_t)(uint16_t)s) << 16;
  return v.f;
}

// GRU MFMA: srcA from VGPR ("v"), srcB (the resident W_hh fragment) pinned to
// an AGPR ("a") -- gfx950 MFMA reads A/B from VGPR or AGPR. This moves the 192
// regs of weight residency OUT of the 128-cap arch-VGPR file into AGPRs, which
// the allocator grants freely (unified file, 2 waves/SIMD). acc stays in arch
// VGPRs: first-K variant literal-0 srcC with early-clobber dest ("=&v", dest
// must not overlap srcA); accumulating variant ties "+v".
__device__ __forceinline__ f32x4 mfma_bf16_0(bf16x8 a, bf16x8 b) {
  f32x4 c;
  asm("v_mfma_f32_16x16x32_bf16 %0, %1, %2, 0" : "=&v"(c) : "v"(a), "a"(b));
  return c;
}
__device__ __forceinline__ void mfma_bf16(f32x4& c, bf16x8 a, bf16x8 b) {
  asm("v_mfma_f32_16x16x32_bf16 %0, %1, %2, %0" : "+v"(c) : "v"(a), "a"(b));
}

// global -> LDS async copy, 16B per lane. LDS dest = wave-uniform base + lane*16.
__device__ __forceinline__ void gload_lds16(const void* g, void* l) {
  __builtin_amdgcn_global_load_lds(
      (const __attribute__((address_space(1))) char*)(uintptr_t)g,
      (__attribute__((address_space(3))) char*)(uintptr_t)l, 16, 0, 0);
}

// ---------------------------------------------------------------------------
// prep: f32->bf16 weight conversions + A2 user-embedding half + W_hh fragment
// pack (fragment-linear so the GRU preamble is 48 coalesced dwordx4 loads).
// ---------------------------------------------------------------------------
__global__ __launch_bounds__(256) void fpp_prep(
    const float* __restrict__ enc_W, const float* __restrict__ W_ih,
    const float* __restrict__ fc_W, const float* __restrict__ user_W,
    const float* __restrict__ W_hh, const int* __restrict__ active_user,
    short* __restrict__ encWb, short* __restrict__ WihB,
    short* __restrict__ fcWb, short* __restrict__ A2,
    short* __restrict__ WhhFrag) {
  const int tid = blockIdx.x * 256 + threadIdx.x;
  const int stride = gridDim.x * 256;
  for (int i = tid; i < V_DIM * H_DIM; i += stride) encWb[i] = f2bf(enc_W[i]);
  for (int i = tid; i < 3 * H_DIM * H_DIM; i += stride) WihB[i] = f2bf(W_ih[i]);
  for (int i = tid; i < V_DIM * 2 * H_DIM; i += stride) fcWb[i] = f2bf(fc_W[i]);
  // A2 rows r = s*64+u ; cols [256,512) = user_W[active_user[u]]
  for (int i = tid; i < 16384 * 256; i += stride) {
    const int row = i >> 8, k = i & 255;
    const int au = active_user[row & 63];
    A2[(int64_t)row * 512 + 256 + k] = f2bf(user_W[(int64_t)au * 256 + k]);
  }
  // WhhFrag[i], i = (((wv*6+tt)*8+kc)*64+lane)*8+j ; holds W_hh[n][k] bf16 with
  // n = (tt>>1)*256 + 32*wv + (tt&1)*16 + (lane&15), k = kc*32 + (lane>>4)*8 + j
  for (int i = tid; i < 768 * 256; i += stride) {
    const int j = i & 7, ln = (i >> 3) & 63, kc = (i >> 9) & 7, t12 = i >> 12;
    const int tt = t12 % 6, wvv = t12 / 6;
    const int n = (tt >> 1) * 256 + 32 * wvv + (tt & 1) * 16 + (ln & 15);
    const int k = kc * 32 + (ln >> 4) * 8 + j;
    WhhFrag[i] = f2bf(W_hh[n * 256 + k]);
  }
}

// ---------------------------------------------------------------------------
// GEMM (B^T form): C[m,n] = sum_k A[m,k]*B[n,k] (+bias1[n] (+bias2[n] if n<lim))
// bf16 inputs, f32 accum; 128x128 tile, BK=64, 4 waves, double-buffered LDS,
// global_load_lds staging (m97 structure).
// OMODE: 0 = f32 linear, 1 = bf16 linear, 2 = bf16 gi pair-packed
//        [m][j][tp][{r,z,n,pad}]  (j = (c>>5)*16 + (c&15), tp = (c>>4)&1)
// ---------------------------------------------------------------------------
template <int OMODE>
__global__ __launch_bounds__(256) void fpp_gemm_bt(
    const short* __restrict__ A, const short* __restrict__ B, void* __restrict__ C,
    const float* __restrict__ bias1, const float* __restrict__ bias2, int bias2_limit,
    int M, int N, int K, int ldc, int MT, int NT, int SUPER) {
  // m-supertile mapping: SUPER consecutive m-tiles share the whole B panel in L2
  const int bid = blockIdx.x;
  const int per_super = SUPER * NT;
  const int srow = bid / per_super;
  const int rrem = bid - srow * per_super;
  const int mi = srow * SUPER + (rrem % SUPER);
  const int ni = rrem / SUPER;
  const int m0 = mi * 128, n0 = ni * 128;

  __shared__ __attribute__((aligned(16))) short As[2][128 * 64];
  __shared__ __attribute__((aligned(16))) short Bs[2][128 * 64];

  const int tid = threadIdx.x;
  const int lane = tid & 63;
  const int wv = tid >> 6;
  const int wr = wv >> 1, wc = wv & 1;

  f32x4 acc[4][4];
#pragma unroll
  for (int a_ = 0; a_ < 4; ++a_)
#pragma unroll
    for (int b_ = 0; b_ < 4; ++b_) acc[a_][b_] = f32x4{0.f, 0.f, 0.f, 0.f};

  auto stage = [&](int buf, int k0) {
#pragma unroll
    for (int c = 0; c < 4; ++c) {
      const int chunk = c * 256 + tid;        // 16B chunk id
      const int row = chunk >> 3, kc8 = chunk & 7;
      int gr = m0 + row; gr = (gr < M) ? gr : (M - 1);
      gload_lds16(A + (int64_t)gr * K + k0 + kc8 * 8,
                  (char*)&As[buf][0] + (c * 256 + wv * 64) * 16);
    }
#pragma unroll
    for (int c = 0; c < 4; ++c) {
      const int chunk = c * 256 + tid;
      const int row = chunk >> 3, kc8 = chunk & 7;
      int gn = n0 + row; gn = (gn < N) ? gn : (N - 1);
      gload_lds16(B + (int64_t)gn * K + k0 + kc8 * 8,
                  (char*)&Bs[buf][0] + (c * 256 + wv * 64) * 16);
    }
  };

  const int nk = K >> 6;
  stage(0, 0);
  asm volatile("s_waitcnt vmcnt(0)" ::: "memory");
  __syncthreads();
  for (int ks = 0; ks < nk; ++ks) {
    const int cur = ks & 1;
    if (ks + 1 < nk) stage(cur ^ 1, (ks + 1) << 6);  // async prefetch next K-tile
#pragma unroll
    for (int kk = 0; kk < 2; ++kk) {
      bf16x8 af[4], bfr[4];
#pragma unroll
      for (int mt = 0; mt < 4; ++mt)
        af[mt] = *(const bf16x8*)&As[cur][(wr * 64 + mt * 16 + (lane & 15)) * 64 +
                                          kk * 32 + (lane >> 4) * 8];
#pragma unroll
      for (int nt = 0; nt < 4; ++nt)
        bfr[nt] = *(const bf16x8*)&Bs[cur][(wc * 64 + nt * 16 + (lane & 15)) * 64 +
                                           kk * 32 + (lane >> 4) * 8];
#pragma unroll
      for (int mt = 0; mt < 4; ++mt)
#pragma unroll
        for (int nt = 0; nt < 4; ++nt)
          acc[mt][nt] = __builtin_amdgcn_mfma_f32_16x16x32_bf16(
              af[mt], bfr[nt], acc[mt][nt], 0, 0, 0);
    }
    asm volatile("s_waitcnt vmcnt(0)" ::: "memory");
    __syncthreads();
  }

  // epilogue: D layout row=(lane>>4)*4+r (M dim), col=lane&15 (N dim)
#pragma unroll
  for (int nt = 0; nt < 4; ++nt) {
    const int col = n0 + wc * 64 + nt * 16 + (lane & 15);
    if (col >= N) continue;
    float badd = 0.f;
    if (bias1) badd += bias1[col];
    if (bias2 && col < bias2_limit) badd += bias2[col];
#pragma unroll
    for (int mt = 0; mt < 4; ++mt) {
      const int rbase = m0 + wr * 64 + mt * 16 + (lane >> 4) * 4;
#pragma unroll
      for (int r = 0; r < 4; ++r) {
        const int row = rbase + r;
        if (row < M) {
          const float v = acc[mt][nt][r] + badd;
          if (OMODE == 0)
            ((float*)C)[(int64_t)row * ldc + col] = v;
          else if (OMODE == 1)
            ((short*)C)[(int64_t)row * ldc + col] = f2bf(v);
          else {
            // pair-packed: c = col&255, gate = col>>8
            const int cc = col & 255;
            const int jj = ((cc >> 5) << 4) + (cc & 15);
            ((short*)C)[(int64_t)row * 1024 + jj * 8 + ((cc >> 4) & 1) * 4 +
                        (col >> 8)] = f2bf(v);
          }
        }
      }
    }
  }
}

// ---------------------------------------------------------------------------
// GRU: 4 blocks x 16 users x 8 waves, 2 waves/SIMD. W_hh bf16 fragments
// resident in 192 AGPRs ("a" srcB constraint) -- outside the 128-cap arch
// VGPR file, so they cannot be spilled. acc/gates in arch VGPRs (~100 used).
// Fence+s_barrier+nops fused in single asm blobs (atomic). Counted vmcnt(12):
// gout stores and next-step gi loads stay in flight across barriers; every
// iteration stages (wrapped at s=255) so the drain count is uniform & sound.
// ---------------------------------------------------------------------------
__global__ __attribute__((amdgpu_waves_per_eu(2, 2))) __launch_bounds__(512)
void fpp_gru(
    const int* __restrict__ x, const float* __restrict__ h0,
    const short* __restrict__ WhhFrag, const float* __restrict__ b_hh,
    const short* __restrict__ giV, float* __restrict__ out,
    float* __restrict__ hlast) {
  __shared__ __attribute__((aligned(16))) short h_lds[16 * 264];        // 8448 B
  __shared__ __attribute__((aligned(16))) short gi_lds[2][16 * 1024];   // 65536 B
  __shared__ __attribute__((aligned(16))) uint16_t x_lds[256 * 16];     // 8192 B

  const int tid = threadIdx.x;
  const int lane = tid & 63;
  const int wv = tid >> 6;  // wave 0..7
  const int u0 = blockIdx.x * 16;
  const int g = lane >> 4;
  const int lo = lane & 15;

  for (int i = tid; i < 256 * 16; i += 512)
    x_lds[i] = (uint16_t)x[(i >> 4) * 64 + u0 + (i & 15)];

  // preload W_hh B-fragments: 48 coalesced dwordx4 loads -> AGPR residency
  // (one-time v_accvgpr_write here; far from loop MFMAs -> no hazard window)
  bf16x8 Wf[6][8];
  {
    const bf16x8* wfp = (const bf16x8*)WhhFrag;
#pragma unroll
    for (int tt = 0; tt < 6; ++tt)
#pragma unroll
      for (int kc = 0; kc < 8; ++kc)
        Wf[tt][kc] = wfp[((wv * 6 + tt) * 8 + kc) * 64 + lane];
  }
  // b_hh for n-gate (r/z parts folded into giV); applied in gate phase
  const float bhh0 = b_hh[512 + 32 * wv + lo];
  const float bhh1 = b_hh[512 + 32 * wv + 16 + lo];

  // h cells owned by this lane: u = g*4+r, c = 32w + tp*16 + lo
  float hreg[2][4];
#pragma unroll
  for (int tp = 0; tp < 2; ++tp)
#pragma unroll
    for (int r = 0; r < 4; ++r) {
      const int u = g * 4 + r, c = 32 * wv + tp * 16 + lo;
      const float v = h0[(u0 + u) * 256 + c];
      hreg[tp][r] = v;
      h_lds[u * 264 + c] = f2bf(v);
    }
  __syncthreads();  // x_lds + h_lds visible (prologue: full sync ok)

  // stage gi rows (pair-packed, 2KB/user) for step ss into buffer buf
  auto stage_gi = [&](int buf, int ss) {
    const int xid0 = x_lds[ss * 16 + 2 * wv];
    const int xid1 = x_lds[ss * 16 + 2 * wv + 1];
#pragma unroll
    for (int c = 0; c < 4; ++c) {
      const int p = c * 64 + lane;     // chunk 0..255 over the 2-row region
      const int xid = (p >= 128) ? xid1 : xid0;
      const int pin = p & 127;         // 16B chunk within row
      gload_lds16(giV + (int64_t)xid * 1024 + pin * 8,
                  (char*)gi_lds[buf] + wv * 4096 + c * 1024);
    }
  };

  stage_gi(0, 0);
  asm volatile("s_waitcnt vmcnt(0) lgkmcnt(0)\n\ts_barrier" ::: "memory");

  for (int s = 0; s < 256; ++s) {
    // Always stage (wrap at 255 -> harmless row into the dead buffer) so the
    // VM queue shape is identical every iteration: vmcnt(12) below provably
    // drains [S8(s-2), L4(gi s)] and keeps [S8(s-1), L4(gi s+1)] in flight.
    stage_gi((s + 1) & 1, (s + 1) & 255);

    // gh = h @ W_hh^T : 48 MFMAs; kc=0 uses literal-0 srcC (no init copies)
    f32x4 acc[6];
    {
      const bf16x8 a0 = *(const bf16x8*)&h_lds[lo * 264 + g * 8];
#pragma unroll
      for (int tt = 0; tt < 6; ++tt) acc[tt] = mfma_bf16_0(a0, Wf[tt][0]);
    }
#pragma unroll
    for (int kc = 1; kc < 8; ++kc) {
      const bf16x8 a = *(const bf16x8*)&h_lds[lo * 264 + kc * 32 + g * 8];
#pragma unroll
      for (int tt = 0; tt < 6; ++tt) mfma_bf16(acc[tt], a, Wf[tt][kc]);
    }

    // barrier1 (atomic blob): h_lds reads done; gi[s&1] landed (see above).
    // s_nops: MFMA-write -> VALU-read pipeline guard (asm opaque to HR).
    asm volatile(
        "s_waitcnt vmcnt(12) lgkmcnt(0)\n\t"
        "s_barrier\n\t"
        "s_nop 7\n\t"
        "s_nop 7" ::: "memory");

    // gates: acc tiles align with cell ownership; gi via 4 x ds_read_b128.
    const char* gbase = (const char*)gi_lds[s & 1];
#pragma unroll
    for (int r = 0; r < 4; ++r) {
      const int u = g * 4 + r;
      const bf16x8 gv = *(const bf16x8*)(gbase + u * 2048 + (wv * 16 + lo) * 16);
#pragma unroll
      for (int tp = 0; tp < 2; ++tp) {
        const int c = 32 * wv + tp * 16 + lo;
        const float gir = bf2f(gv[tp * 4 + 0]);
        const float giz = bf2f(gv[tp * 4 + 1]);
        const float gin = bf2f(gv[tp * 4 + 2]);
        const float bhh = tp ? bhh1 : bhh0;
        const float xr = acc[0 + tp][r] + gir;
        const float rr = __builtin_amdgcn_rcpf(1.f + __builtin_amdgcn_exp2f(-1.4426950408889634f * xr));
        const float xz = acc[2 + tp][r] + giz;
        const float zz = __builtin_amdgcn_rcpf(1.f + __builtin_amdgcn_exp2f(-1.4426950408889634f * xz));
        float xn = gin + rr * (acc[4 + tp][r] + bhh);
        xn = fminf(fmaxf(xn, -12.f), 12.f);
        const float E = __builtin_amdgcn_exp2f(2.8853900817779268f * xn);
        const float nn = (E - 1.f) * __builtin_amdgcn_rcpf(E + 1.f);
        const float hv = nn + zz * (hreg[tp][r] - nn);
        hreg[tp][r] = hv;
        h_lds[u * 264 + c] = f2bf(hv);
        out[((int64_t)s * 64 + u0 + u) * 256 + c] = hv;  // store NOT awaited
      }
    }
    // barrier2 (atomic blob): new h (ds_write) visible; vm ops stay in flight.
    asm volatile(
        "s_waitcnt lgkmcnt(0)\n\t"
        "s_barrier" ::: "memory");
  }

#pragma unroll
  for (int tp = 0; tp < 2; ++tp)
#pragma unroll
    for (int r = 0; r < 4; ++r) {
      const int u = g * 4 + r, c = 32 * wv + tp * 16 + lo;
      hlast[(u0 + u) * 256 + c] = hreg[tp][r];
    }
}

// ---------------------------------------------------------------------------
// attention: per (u, i-block of 64): loop causal j-blocks; w in LDS; weighted
// sum of GRU hiddens; writes bf16 into A2[:, 0:256]. f32 vector math.
// ---------------------------------------------------------------------------
__global__ __launch_bounds__(256) void fpp_attn(
    const float* __restrict__ t_g, const float* __restrict__ s_g,
    const float* __restrict__ gout, short* __restrict__ A2) {
  const int u = blockIdx.x;   // 0..63
  const int ib = blockIdx.y;  // 0..3
  const int tid = threadIdx.x;
  const int iloc = tid >> 2;  // 0..63
  const int q = tid & 3;      // h quarter (64 each)

  __shared__ __attribute__((aligned(16))) float out_lds[64][272];  // q-seg stride 68
  __shared__ __attribute__((aligned(16))) float w_lds[64][65];
  __shared__ float ti[64], si0[64], si1[64], tj[64], sj0[64], sj1[64], sum_lds[64];

  if (tid < 64) {
    const int ig = ib * 64 + tid;
    ti[tid] = t_g[ig * 64 + u];
    si0[tid] = s_g[(ig * 64 + u) * 2 + 0];
    si1[tid] = s_g[(ig * 64 + u) * 2 + 1];
    sum_lds[tid] = 0.f;
  }

  f32x4 accv[16];
#pragma unroll
  for (int hh = 0; hh < 16; ++hh) accv[hh] = f32x4{0.f, 0.f, 0.f, 0.f};

  const int igl = ib * 64 + iloc;

  for (int jb = 0; jb <= ib; ++jb) {
    __syncthreads();  // protect LDS vs previous iteration readers
    {
      const int jj = tid >> 2;
      const float* src = gout + ((int64_t)(jb * 64 + jj) * 64 + u) * 256 + q * 64;
#pragma unroll
      for (int hh = 0; hh < 16; ++hh)
        *(f32x4*)&out_lds[jj][q * 68 + hh * 4] = *(const f32x4*)(src + hh * 4);
    }
    if (tid < 64) {
      const int jg = jb * 64 + tid;
      tj[tid] = t_g[jg * 64 + u];
      sj0[tid] = s_g[(jg * 64 + u) * 2 + 0];
      sj1[tid] = s_g[(jg * 64 + u) * 2 + 1];
    }
    __syncthreads();
    {
      const float tiv = ti[iloc], p0 = si0[iloc], p1 = si1[iloc];
#pragma unroll
      for (int jj = 0; jj < 16; ++jj) {
        const int j = q * 16 + jj;
        const int jgl = jb * 64 + j;
        const float dt = tiv - tj[j];
        // f_t = (cos(2*pi*dt)+1)*0.5*exp(-0.1*dt); v_cos takes revolutions
        const float ft = (__builtin_amdgcn_cosf(dt) + 1.f) * 0.5f *
                         __builtin_amdgcn_exp2f(-0.14426950408889634f * dt);
        const float dx = p0 - sj0[j], dy = p1 - sj1[j];
        const float ds = __builtin_amdgcn_sqrtf(dx * dx + dy * dy);
        const float fs = __builtin_amdgcn_exp2f(-144.26950408889634f * ds);
        float wvv = ft * fs + 1e-10f;
        if (jgl > igl) wvv = 0.f;  // causal
        w_lds[iloc][j] = wvv;
      }
    }
    __syncthreads();
    if (tid < 64) {
      float sm = 0.f;
#pragma unroll
      for (int j = 0; j < 64; ++j) sm += w_lds[tid][j];
      sum_lds[tid] += sm;
    }
    for (int j = 0; j < 64; ++j) {
      const float wvv = w_lds[iloc][j];
#pragma unroll
      for (int hh = 0; hh < 16; ++hh) {
        const f32x4 o = *(const f32x4*)&out_lds[j][q * 68 + hh * 4];
        accv[hh] += o * wvv;
      }
    }
  }
  __syncthreads();
  const float inv = 1.f / sum_lds[iloc];
  short* dst = A2 + (int64_t)((ib * 64 + iloc) * 64 + u) * 512 + q * 64;
#pragma unroll
  for (int hh = 0; hh < 16; ++hh) {
    const f32x4 v = accv[hh] * inv;
    short4 sv;
    sv.x = f2bf(v[0]); sv.y = f2bf(v[1]); sv.z = f2bf(v[2]); sv.w = f2bf(v[3]);
    *(short4*)(dst + hh * 4) = sv;
  }
}

// ---------------------------------------------------------------------------
extern "C" void kernel_launch(void* const* d_in, const int* in_sizes, int n_in,
                              void* d_out, int out_size, void* d_ws, size_t ws_size,
                              hipStream_t stream) {
  (void)in_sizes; (void)n_in; (void)out_size; (void)ws_size;
  const int*   x      = (const int*)  d_in[0];
  const float* t      = (const float*)d_in[1];
  const float* s      = (const float*)d_in[2];
  // d_in[3], d_in[4] (y_t, y_s) unused by reference
  const float* h0     = (const float*)d_in[5];
  const int*   au     = (const int*)  d_in[6];
  const float* enc_W  = (const float*)d_in[7];
  const float* user_W = (const float*)d_in[8];
  const float* W_ih   = (const float*)d_in[9];
  const float* W_hh   = (const float*)d_in[10];
  const float* b_ih   = (const float*)d_in[11];
  const float* b_hh   = (const float*)d_in[12];
  const float* fc_W   = (const float*)d_in[13];
  const float* fc_b   = (const float*)d_in[14];

  float* y = (float*)d_out;
  float* hlast = y + Y_ELEMS;

  char* ws = (char*)d_ws;
  short* giV   = (short*)(ws + 0);          // 10000x256x4 bf16, pair-packed
  short* A2    = (short*)(ws + 20480000);   // 16384x512 bf16
  short* fcWb  = (short*)(ws + 37257216);   // 10000x512 bf16
  short* encWb = (short*)(ws + 47497216);   // 10000x256 bf16
  short* WihB  = (short*)(ws + 52617216);   // 768x256 bf16
  float* gout  = (float*)(ws + 53010432);   // 256x64x256 f32 GRU hiddens
  // WhhFrag scratch lives inside d_out's y region (written by prep, read by
  // GRU, overwritten by the final GEMM) to avoid growing ws usage.
  short* WhhFrag = (short*)(y + 80000000);  // 768x256 bf16, fragment-linear

  fpp_prep<<<1024, 256, 0, stream>>>(enc_W, W_ih, fc_W, user_W, W_hh, au,
                                     encWb, WihB, fcWb, A2, WhhFrag);
  // giV = enc_W @ W_ih.T + b_ih (+ b_hh for n<512); bf16, pair-packed layout
  fpp_gemm_bt<2><<<79 * 6, 256, 0, stream>>>(encWb, WihB, giV, b_ih, b_hh, 512,
                                             10000, 768, 256, 0, 79, 6, 1);
  fpp_gru<<<4, 512, 0, stream>>>(x, h0, WhhFrag, b_hh, giV, gout, hlast);
  fpp_attn<<<dim3(64, 4), 256, 0, stream>>>(t, s, gout, A2);
  // y = A2 @ fc_W.T + fc_b ; f32 out
  fpp_gemm_bt<0><<<128 * 79, 256, 0, stream>>>(A2, fcWb, y, fc_b, nullptr, 0,
                                               16384, 10000, 512, 10000, 128, 79, 8);
}

// Round 8
// 1299.112 us; speedup vs baseline: 1.0004x; 1.0004x over previous
//
#include <hip/hip_runtime.h>
#include <stdint.h>

// FlashbackPlusPlus: embed->GRU->spatiotemporal causal attention->FC
// S=256 U=64 H=256 V=10000
#define S_LEN 256
#define U_LEN 64
#define H_DIM 256
#define V_DIM 10000
#define Y_ELEMS 163840000LL  // S*U*V

typedef short bf16x8 __attribute__((ext_vector_type(8)));
typedef float f32x4 __attribute__((ext_vector_type(4)));

__device__ __forceinline__ short f2bf(float f) {
  union { float f; uint32_t u; } v; v.f = f;
  uint32_t r = v.u + 0x7FFFu + ((v.u >> 16) & 1u);  // RNE
  return (short)(r >> 16);
}
__device__ __forceinline__ float bf2f(short s) {
  union { uint32_t u; float f; } v; v.u = ((uint32_t)(uint16_t)s) << 16;
  return v.f;
}

// GRU MFMA: srcA from VGPR ("v"), srcB (resident W_hh fragment) from AGPR
// ("a"). acc in arch VGPRs: first-K variant literal-0 srcC with early-clobber
// dest ("=&v"); accumulating variant ties "+v".
__device__ __forceinline__ f32x4 mfma_bf16_0(bf16x8 a, bf16x8 b) {
  f32x4 c;
  asm("v_mfma_f32_16x16x32_bf16 %0, %1, %2, 0" : "=&v"(c) : "v"(a), "a"(b));
  return c;
}
__device__ __forceinline__ void mfma_bf16(f32x4& c, bf16x8 a, bf16x8 b) {
  asm("v_mfma_f32_16x16x32_bf16 %0, %1, %2, %0" : "+v"(c) : "v"(a), "a"(b));
}

// global -> LDS async copy, 16B per lane. LDS dest = wave-uniform base + lane*16.
__device__ __forceinline__ void gload_lds16(const void* g, void* l) {
  __builtin_amdgcn_global_load_lds(
      (const __attribute__((address_space(1))) char*)(uintptr_t)g,
      (__attribute__((address_space(3))) char*)(uintptr_t)l, 16, 0, 0);
}

// ---------------------------------------------------------------------------
// prep: f32->bf16 weight conversions + A2 user-embedding half + W_hh fragment
// pack (fragment-linear so the GRU preamble is 48 coalesced dwordx4 loads).
// ---------------------------------------------------------------------------
__global__ __launch_bounds__(256) void fpp_prep(
    const float* __restrict__ enc_W, const float* __restrict__ W_ih,
    const float* __restrict__ fc_W, const float* __restrict__ user_W,
    const float* __restrict__ W_hh, const int* __restrict__ active_user,
    short* __restrict__ encWb, short* __restrict__ WihB,
    short* __restrict__ fcWb, short* __restrict__ A2,
    short* __restrict__ WhhFrag) {
  const int tid = blockIdx.x * 256 + threadIdx.x;
  const int stride = gridDim.x * 256;
  for (int i = tid; i < V_DIM * H_DIM; i += stride) encWb[i] = f2bf(enc_W[i]);
  for (int i = tid; i < 3 * H_DIM * H_DIM; i += stride) WihB[i] = f2bf(W_ih[i]);
  for (int i = tid; i < V_DIM * 2 * H_DIM; i += stride) fcWb[i] = f2bf(fc_W[i]);
  // A2 rows r = s*64+u ; cols [256,512) = user_W[active_user[u]]
  for (int i = tid; i < 16384 * 256; i += stride) {
    const int row = i >> 8, k = i & 255;
    const int au = active_user[row & 63];
    A2[(int64_t)row * 512 + 256 + k] = f2bf(user_W[(int64_t)au * 256 + k]);
  }
  // WhhFrag[i], i = (((wv*6+tt)*8+kc)*64+lane)*8+j ; holds W_hh[n][k] bf16 with
  // n = (tt>>1)*256 + 32*wv + (tt&1)*16 + (lane&15), k = kc*32 + (lane>>4)*8 + j
  for (int i = tid; i < 768 * 256; i += stride) {
    const int j = i & 7, ln = (i >> 3) & 63, kc = (i >> 9) & 7, t12 = i >> 12;
    const int tt = t12 % 6, wvv = t12 / 6;
    const int n = (tt >> 1) * 256 + 32 * wvv + (tt & 1) * 16 + (ln & 15);
    const int k = kc * 32 + (ln >> 4) * 8 + j;
    WhhFrag[i] = f2bf(W_hh[n * 256 + k]);
  }
}

// ---------------------------------------------------------------------------
// GEMM (B^T form): C[m,n] = sum_k A[m,k]*B[n,k] (+bias1[n] (+bias2[n] if n<lim))
// bf16 inputs, f32 accum; 128x128 tile, BK=64, 4 waves, double-buffered LDS,
// global_load_lds staging (m97 structure).
// OMODE: 0 = f32 linear, 1 = bf16 linear, 2 = bf16 gi pair-packed
//        [m][j][tp][{r,z,n,pad}]  (j = (c>>5)*16 + (c&15), tp = (c>>4)&1)
// ---------------------------------------------------------------------------
template <int OMODE>
__global__ __launch_bounds__(256) void fpp_gemm_bt(
    const short* __restrict__ A, const short* __restrict__ B, void* __restrict__ C,
    const float* __restrict__ bias1, const float* __restrict__ bias2, int bias2_limit,
    int M, int N, int K, int ldc, int MT, int NT, int SUPER) {
  // m-supertile mapping: SUPER consecutive m-tiles share the whole B panel in L2
  const int bid = blockIdx.x;
  const int per_super = SUPER * NT;
  const int srow = bid / per_super;
  const int rrem = bid - srow * per_super;
  const int mi = srow * SUPER + (rrem % SUPER);
  const int ni = rrem / SUPER;
  const int m0 = mi * 128, n0 = ni * 128;

  __shared__ __attribute__((aligned(16))) short As[2][128 * 64];
  __shared__ __attribute__((aligned(16))) short Bs[2][128 * 64];

  const int tid = threadIdx.x;
  const int lane = tid & 63;
  const int wv = tid >> 6;
  const int wr = wv >> 1, wc = wv & 1;

  f32x4 acc[4][4];
#pragma unroll
  for (int a_ = 0; a_ < 4; ++a_)
#pragma unroll
    for (int b_ = 0; b_ < 4; ++b_) acc[a_][b_] = f32x4{0.f, 0.f, 0.f, 0.f};

  auto stage = [&](int buf, int k0) {
#pragma unroll
    for (int c = 0; c < 4; ++c) {
      const int chunk = c * 256 + tid;        // 16B chunk id
      const int row = chunk >> 3, kc8 = chunk & 7;
      int gr = m0 + row; gr = (gr < M) ? gr : (M - 1);
      gload_lds16(A + (int64_t)gr * K + k0 + kc8 * 8,
                  (char*)&As[buf][0] + (c * 256 + wv * 64) * 16);
    }
#pragma unroll
    for (int c = 0; c < 4; ++c) {
      const int chunk = c * 256 + tid;
      const int row = chunk >> 3, kc8 = chunk & 7;
      int gn = n0 + row; gn = (gn < N) ? gn : (N - 1);
      gload_lds16(B + (int64_t)gn * K + k0 + kc8 * 8,
                  (char*)&Bs[buf][0] + (c * 256 + wv * 64) * 16);
    }
  };

  const int nk = K >> 6;
  stage(0, 0);
  asm volatile("s_waitcnt vmcnt(0)" ::: "memory");
  __syncthreads();
  for (int ks = 0; ks < nk; ++ks) {
    const int cur = ks & 1;
    if (ks + 1 < nk) stage(cur ^ 1, (ks + 1) << 6);  // async prefetch next K-tile
#pragma unroll
    for (int kk = 0; kk < 2; ++kk) {
      bf16x8 af[4], bfr[4];
#pragma unroll
      for (int mt = 0; mt < 4; ++mt)
        af[mt] = *(const bf16x8*)&As[cur][(wr * 64 + mt * 16 + (lane & 15)) * 64 +
                                          kk * 32 + (lane >> 4) * 8];
#pragma unroll
      for (int nt = 0; nt < 4; ++nt)
        bfr[nt] = *(const bf16x8*)&Bs[cur][(wc * 64 + nt * 16 + (lane & 15)) * 64 +
                                           kk * 32 + (lane >> 4) * 8];
#pragma unroll
      for (int mt = 0; mt < 4; ++mt)
#pragma unroll
        for (int nt = 0; nt < 4; ++nt)
          acc[mt][nt] = __builtin_amdgcn_mfma_f32_16x16x32_bf16(
              af[mt], bfr[nt], acc[mt][nt], 0, 0, 0);
    }
    asm volatile("s_waitcnt vmcnt(0)" ::: "memory");
    __syncthreads();
  }

  // epilogue: D layout row=(lane>>4)*4+r (M dim), col=lane&15 (N dim)
#pragma unroll
  for (int nt = 0; nt < 4; ++nt) {
    const int col = n0 + wc * 64 + nt * 16 + (lane & 15);
    if (col >= N) continue;
    float badd = 0.f;
    if (bias1) badd += bias1[col];
    if (bias2 && col < bias2_limit) badd += bias2[col];
#pragma unroll
    for (int mt = 0; mt < 4; ++mt) {
      const int rbase = m0 + wr * 64 + mt * 16 + (lane >> 4) * 4;
#pragma unroll
      for (int r = 0; r < 4; ++r) {
        const int row = rbase + r;
        if (row < M) {
          const float v = acc[mt][nt][r] + badd;
          if (OMODE == 0)
            ((float*)C)[(int64_t)row * ldc + col] = v;
          else if (OMODE == 1)
            ((short*)C)[(int64_t)row * ldc + col] = f2bf(v);
          else {
            // pair-packed: c = col&255, gate = col>>8
            const int cc = col & 255;
            const int jj = ((cc >> 5) << 4) + (cc & 15);
            ((short*)C)[(int64_t)row * 1024 + jj * 8 + ((cc >> 4) & 1) * 4 +
                        (col >> 8)] = f2bf(v);
          }
        }
      }
    }
  }
}

// ---------------------------------------------------------------------------
// GRU: 4 blocks x 16 users x 8 waves, 2 waves/SIMD. The 48 W_hh fragments are
// loaded ONCE and pinned into AGPRs through an empty inline-asm def -- an
// asm-produced value cannot be rematerialized from memory, so the loop's
// "memory"-clobber barriers can no longer force a per-step re-load (the root
// cause of the 3000+ cyc/step L2 traffic in R1-R7). MFMAs consume them via
// "a" srcB. Counted vmcnt(12) barriers as in R7 (passed).
// ---------------------------------------------------------------------------
__global__ __attribute__((amdgpu_waves_per_eu(2, 2))) __launch_bounds__(512)
void fpp_gru(
    const int* __restrict__ x, const float* __restrict__ h0,
    const short* __restrict__ WhhFrag, const float* __restrict__ b_hh,
    const short* __restrict__ giV, float* __restrict__ out,
    float* __restrict__ hlast) {
  __shared__ __attribute__((aligned(16))) short h_lds[16 * 264];        // 8448 B
  __shared__ __attribute__((aligned(16))) short gi_lds[2][16 * 1024];   // 65536 B
  __shared__ __attribute__((aligned(16))) uint16_t x_lds[256 * 16];     // 8192 B

  const int tid = threadIdx.x;
  const int lane = tid & 63;
  const int wv = tid >> 6;  // wave 0..7
  const int u0 = blockIdx.x * 16;
  const int g = lane >> 4;
  const int lo = lane & 15;

  for (int i = tid; i < 256 * 16; i += 512)
    x_lds[i] = (uint16_t)x[(i >> 4) * 64 + u0 + (i & 15)];

  // preload W_hh B-fragments, pinning each into AGPRs as an OPAQUE asm value:
  // the compiler cannot re-load (rematerialize) these inside the loop, no
  // matter what memory clobbers the barriers carry.
  bf16x8 Wf[6][8];
  {
    const bf16x8* wfp = (const bf16x8*)WhhFrag;
#pragma unroll
    for (int tt = 0; tt < 6; ++tt)
#pragma unroll
      for (int kc = 0; kc < 8; ++kc) {
        bf16x8 tmp = wfp[((wv * 6 + tt) * 8 + kc) * 64 + lane];
        asm("" : "=a"(Wf[tt][kc]) : "0"(tmp));  // pin: value now AGPR-resident
      }
  }
  // b_hh for n-gate (r/z parts folded into giV); applied in gate phase
  const float bhh0 = b_hh[512 + 32 * wv + lo];
  const float bhh1 = b_hh[512 + 32 * wv + 16 + lo];

  // h cells owned by this lane: u = g*4+r, c = 32w + tp*16 + lo
  float hreg[2][4];
#pragma unroll
  for (int tp = 0; tp < 2; ++tp)
#pragma unroll
    for (int r = 0; r < 4; ++r) {
      const int u = g * 4 + r, c = 32 * wv + tp * 16 + lo;
      const float v = h0[(u0 + u) * 256 + c];
      hreg[tp][r] = v;
      h_lds[u * 264 + c] = f2bf(v);
    }
  __syncthreads();  // x_lds + h_lds visible (prologue: full sync ok)

  // stage gi rows (pair-packed, 2KB/user) for step ss into buffer buf
  auto stage_gi = [&](int buf, int ss) {
    const int xid0 = x_lds[ss * 16 + 2 * wv];
    const int xid1 = x_lds[ss * 16 + 2 * wv + 1];
#pragma unroll
    for (int c = 0; c < 4; ++c) {
      const int p = c * 64 + lane;     // chunk 0..255 over the 2-row region
      const int xid = (p >= 128) ? xid1 : xid0;
      const int pin = p & 127;         // 16B chunk within row
      gload_lds16(giV + (int64_t)xid * 1024 + pin * 8,
                  (char*)gi_lds[buf] + wv * 4096 + c * 1024);
    }
  };

  stage_gi(0, 0);
  asm volatile("s_waitcnt vmcnt(0) lgkmcnt(0)\n\ts_barrier" ::: "memory");

  for (int s = 0; s < 256; ++s) {
    // Always stage (wrap at 255 -> harmless row into the dead buffer) so the
    // VM queue shape is identical every iteration: vmcnt(12) below provably
    // drains [L4(gi s)] and keeps [S8(s-1), L4(gi s+1)] in flight.
    stage_gi((s + 1) & 1, (s + 1) & 255);

    // gh = h @ W_hh^T : 48 MFMAs; kc=0 uses literal-0 srcC (no init copies)
    f32x4 acc[6];
    {
      const bf16x8 a0 = *(const bf16x8*)&h_lds[lo * 264 + g * 8];
#pragma unroll
      for (int tt = 0; tt < 6; ++tt) acc[tt] = mfma_bf16_0(a0, Wf[tt][0]);
    }
#pragma unroll
    for (int kc = 1; kc < 8; ++kc) {
      const bf16x8 a = *(const bf16x8*)&h_lds[lo * 264 + kc * 32 + g * 8];
#pragma unroll
      for (int tt = 0; tt < 6; ++tt) mfma_bf16(acc[tt], a, Wf[tt][kc]);
    }

    // barrier1 (atomic blob): h_lds reads done; gi[s&1] landed (see above).
    // s_nops: MFMA-write -> VALU-read pipeline guard (asm opaque to HR).
    asm volatile(
        "s_waitcnt vmcnt(12) lgkmcnt(0)\n\t"
        "s_barrier\n\t"
        "s_nop 7\n\t"
        "s_nop 7" ::: "memory");

    // gates: acc tiles align with cell ownership; gi via 4 x ds_read_b128.
    const char* gbase = (const char*)gi_lds[s & 1];
#pragma unroll
    for (int r = 0; r < 4; ++r) {
      const int u = g * 4 + r;
      const bf16x8 gv = *(const bf16x8*)(gbase + u * 2048 + (wv * 16 + lo) * 16);
#pragma unroll
      for (int tp = 0; tp < 2; ++tp) {
        const int c = 32 * wv + tp * 16 + lo;
        const float gir = bf2f(gv[tp * 4 + 0]);
        const float giz = bf2f(gv[tp * 4 + 1]);
        const float gin = bf2f(gv[tp * 4 + 2]);
        const float bhh = tp ? bhh1 : bhh0;
        const float xr = acc[0 + tp][r] + gir;
        const float rr = __builtin_amdgcn_rcpf(1.f + __builtin_amdgcn_exp2f(-1.4426950408889634f * xr));
        const float xz = acc[2 + tp][r] + giz;
        const float zz = __builtin_amdgcn_rcpf(1.f + __builtin_amdgcn_exp2f(-1.4426950408889634f * xz));
        float xn = gin + rr * (acc[4 + tp][r] + bhh);
        xn = fminf(fmaxf(xn, -12.f), 12.f);
        const float E = __builtin_amdgcn_exp2f(2.8853900817779268f * xn);
        const float nn = (E - 1.f) * __builtin_amdgcn_rcpf(E + 1.f);
        const float hv = nn + zz * (hreg[tp][r] - nn);
        hreg[tp][r] = hv;
        h_lds[u * 264 + c] = f2bf(hv);
        out[((int64_t)s * 64 + u0 + u) * 256 + c] = hv;  // store NOT awaited
      }
    }
    // barrier2 (atomic blob): new h (ds_write) visible; vm ops stay in flight.
    asm volatile(
        "s_waitcnt lgkmcnt(0)\n\t"
        "s_barrier" ::: "memory");
  }

#pragma unroll
  for (int tp = 0; tp < 2; ++tp)
#pragma unroll
    for (int r = 0; r < 4; ++r) {
      const int u = g * 4 + r, c = 32 * wv + tp * 16 + lo;
      hlast[(u0 + u) * 256 + c] = hreg[tp][r];
    }
}

// ---------------------------------------------------------------------------
// attention: per (u, i-block of 64): loop causal j-blocks; w in LDS; weighted
// sum of GRU hiddens; writes bf16 into A2[:, 0:256]. f32 vector math.
// ---------------------------------------------------------------------------
__global__ __launch_bounds__(256) void fpp_attn(
    const float* __restrict__ t_g, const float* __restrict__ s_g,
    const float* __restrict__ gout, short* __restrict__ A2) {
  const int u = blockIdx.x;   // 0..63
  const int ib = blockIdx.y;  // 0..3
  const int tid = threadIdx.x;
  const int iloc = tid >> 2;  // 0..63
  const int q = tid & 3;      // h quarter (64 each)

  __shared__ __attribute__((aligned(16))) float out_lds[64][272];  // q-seg stride 68
  __shared__ __attribute__((aligned(16))) float w_lds[64][65];
  __shared__ float ti[64], si0[64], si1[64], tj[64], sj0[64], sj1[64], sum_lds[64];

  if (tid < 64) {
    const int ig = ib * 64 + tid;
    ti[tid] = t_g[ig * 64 + u];
    si0[tid] = s_g[(ig * 64 + u) * 2 + 0];
    si1[tid] = s_g[(ig * 64 + u) * 2 + 1];
    sum_lds[tid] = 0.f;
  }

  f32x4 accv[16];
#pragma unroll
  for (int hh = 0; hh < 16; ++hh) accv[hh] = f32x4{0.f, 0.f, 0.f, 0.f};

  const int igl = ib * 64 + iloc;

  for (int jb = 0; jb <= ib; ++jb) {
    __syncthreads();  // protect LDS vs previous iteration readers
    {
      const int jj = tid >> 2;
      const float* src = gout + ((int64_t)(jb * 64 + jj) * 64 + u) * 256 + q * 64;
#pragma unroll
      for (int hh = 0; hh < 16; ++hh)
        *(f32x4*)&out_lds[jj][q * 68 + hh * 4] = *(const f32x4*)(src + hh * 4);
    }
    if (tid < 64) {
      const int jg = jb * 64 + tid;
      tj[tid] = t_g[jg * 64 + u];
      sj0[tid] = s_g[(jg * 64 + u) * 2 + 0];
      sj1[tid] = s_g[(jg * 64 + u) * 2 + 1];
    }
    __syncthreads();
    {
      const float tiv = ti[iloc], p0 = si0[iloc], p1 = si1[iloc];
#pragma unroll
      for (int jj = 0; jj < 16; ++jj) {
        const int j = q * 16 + jj;
        const int jgl = jb * 64 + j;
        const float dt = tiv - tj[j];
        // f_t = (cos(2*pi*dt)+1)*0.5*exp(-0.1*dt); v_cos takes revolutions
        const float ft = (__builtin_amdgcn_cosf(dt) + 1.f) * 0.5f *
                         __builtin_amdgcn_exp2f(-0.14426950408889634f * dt);
        const float dx = p0 - sj0[j], dy = p1 - sj1[j];
        const float ds = __builtin_amdgcn_sqrtf(dx * dx + dy * dy);
        const float fs = __builtin_amdgcn_exp2f(-144.26950408889634f * ds);
        float wvv = ft * fs + 1e-10f;
        if (jgl > igl) wvv = 0.f;  // causal
        w_lds[iloc][j] = wvv;
      }
    }
    __syncthreads();
    if (tid < 64) {
      float sm = 0.f;
#pragma unroll
      for (int j = 0; j < 64; ++j) sm += w_lds[tid][j];
      sum_lds[tid] += sm;
    }
    for (int j = 0; j < 64; ++j) {
      const float wvv = w_lds[iloc][j];
#pragma unroll
      for (int hh = 0; hh < 16; ++hh) {
        const f32x4 o = *(const f32x4*)&out_lds[j][q * 68 + hh * 4];
        accv[hh] += o * wvv;
      }
    }
  }
  __syncthreads();
  const float inv = 1.f / sum_lds[iloc];
  short* dst = A2 + (int64_t)((ib * 64 + iloc) * 64 + u) * 512 + q * 64;
#pragma unroll
  for (int hh = 0; hh < 16; ++hh) {
    const f32x4 v = accv[hh] * inv;
    short4 sv;
    sv.x = f2bf(v[0]); sv.y = f2bf(v[1]); sv.z = f2bf(v[2]); sv.w = f2bf(v[3]);
    *(short4*)(dst + hh * 4) = sv;
  }
}

// ---------------------------------------------------------------------------
extern "C" void kernel_launch(void* const* d_in, const int* in_sizes, int n_in,
                              void* d_out, int out_size, void* d_ws, size_t ws_size,
                              hipStream_t stream) {
  (void)in_sizes; (void)n_in; (void)out_size; (void)ws_size;
  const int*   x      = (const int*)  d_in[0];
  const float* t      = (const float*)d_in[1];
  const float* s      = (const float*)d_in[2];
  // d_in[3], d_in[4] (y_t, y_s) unused by reference
  const float* h0     = (const float*)d_in[5];
  const int*   au     = (const int*)  d_in[6];
  const float* enc_W  = (const float*)d_in[7];
  const float* user_W = (const float*)d_in[8];
  const float* W_ih   = (const float*)d_in[9];
  const float* W_hh   = (const float*)d_in[10];
  const float* b_ih   = (const float*)d_in[11];
  const float* b_hh   = (const float*)d_in[12];
  const float* fc_W   = (const float*)d_in[13];
  const float* fc_b   = (const float*)d_in[14];

  float* y = (float*)d_out;
  float* hlast = y + Y_ELEMS;

  char* ws = (char*)d_ws;
  short* giV   = (short*)(ws + 0);          // 10000x256x4 bf16, pair-packed
  short* A2    = (short*)(ws + 20480000);   // 16384x512 bf16
  short* fcWb  = (short*)(ws + 37257216);   // 10000x512 bf16
  short* encWb = (short*)(ws + 47497216);   // 10000x256 bf16
  short* WihB  = (short*)(ws + 52617216);   // 768x256 bf16
  float* gout  = (float*)(ws + 53010432);   // 256x64x256 f32 GRU hiddens
  // WhhFrag scratch lives inside d_out's y region (written by prep, read by
  // GRU, overwritten by the final GEMM) to avoid growing ws usage.
  short* WhhFrag = (short*)(y + 80000000);  // 768x256 bf16, fragment-linear

  fpp_prep<<<1024, 256, 0, stream>>>(enc_W, W_ih, fc_W, user_W, W_hh, au,
                                     encWb, WihB, fcWb, A2, WhhFrag);
  // giV = enc_W @ W_ih.T + b_ih (+ b_hh for n<512); bf16, pair-packed layout
  fpp_gemm_bt<2><<<79 * 6, 256, 0, stream>>>(encWb, WihB, giV, b_ih, b_hh, 512,
                                             10000, 768, 256, 0, 79, 6, 1);
  fpp_gru<<<4, 512, 0, stream>>>(x, h0, WhhFrag, b_hh, giV, gout, hlast);
  fpp_attn<<<dim3(64, 4), 256, 0, stream>>>(t, s, gout, A2);
  // y = A2 @ fc_W.T + fc_b ; f32 out
  fpp_gemm_bt<0><<<128 * 79, 256, 0, stream>>>(A2, fcWb, y, fc_b, nullptr, 0,
                                               16384, 10000, 512, 10000, 128, 79, 8);
}

// Round 9
// 1237.835 us; speedup vs baseline: 1.0499x; 1.0495x over previous
//
#include <hip/hip_runtime.h>
#include <stdint.h>

// FlashbackPlusPlus: embed->GRU->spatiotemporal causal attention->FC
// S=256 U=64 H=256 V=10000
#define S_LEN 256
#define U_LEN 64
#define H_DIM 256
#define V_DIM 10000
#define Y_ELEMS 163840000LL  // S*U*V

typedef short bf16x8 __attribute__((ext_vector_type(8)));
typedef float f32x4 __attribute__((ext_vector_type(4)));

__device__ __forceinline__ short f2bf(float f) {
  union { float f; uint32_t u; } v; v.f = f;
  uint32_t r = v.u + 0x7FFFu + ((v.u >> 16) & 1u);  // RNE
  return (short)(r >> 16);
}
__device__ __forceinline__ float bf2f(short s) {
  union { uint32_t u; float f; } v; v.u = ((uint32_t)(uint16_t)s) << 16;
  return v.f;
}

// global -> LDS async copy, 16B per lane. LDS dest = wave-uniform base + lane*16.
__device__ __forceinline__ void gload_lds16(const void* g, void* l) {
  __builtin_amdgcn_global_load_lds(
      (const __attribute__((address_space(1))) char*)(uintptr_t)g,
      (__attribute__((address_space(3))) char*)(uintptr_t)l, 16, 0, 0);
}

// ---------------------------------------------------------------------------
// prep: f32->bf16 weight conversions + A2 user-embedding half + W_hh fragment
// pack (fragment-linear so the GRU preamble is 48 coalesced dwordx4 loads).
// ---------------------------------------------------------------------------
__global__ __launch_bounds__(256) void fpp_prep(
    const float* __restrict__ enc_W, const float* __restrict__ W_ih,
    const float* __restrict__ fc_W, const float* __restrict__ user_W,
    const float* __restrict__ W_hh, const int* __restrict__ active_user,
    short* __restrict__ encWb, short* __restrict__ WihB,
    short* __restrict__ fcWb, short* __restrict__ A2,
    short* __restrict__ WhhFrag) {
  const int tid = blockIdx.x * 256 + threadIdx.x;
  const int stride = gridDim.x * 256;
  for (int i = tid; i < V_DIM * H_DIM; i += stride) encWb[i] = f2bf(enc_W[i]);
  for (int i = tid; i < 3 * H_DIM * H_DIM; i += stride) WihB[i] = f2bf(W_ih[i]);
  for (int i = tid; i < V_DIM * 2 * H_DIM; i += stride) fcWb[i] = f2bf(fc_W[i]);
  // A2 rows r = s*64+u ; cols [256,512) = user_W[active_user[u]]
  for (int i = tid; i < 16384 * 256; i += stride) {
    const int row = i >> 8, k = i & 255;
    const int au = active_user[row & 63];
    A2[(int64_t)row * 512 + 256 + k] = f2bf(user_W[(int64_t)au * 256 + k]);
  }
  // WhhFrag[i], i = (((wv*6+tt)*8+kc)*64+lane)*8+j ; holds W_hh[n][k] bf16 with
  // n = (tt>>1)*256 + 32*wv + (tt&1)*16 + (lane&15), k = kc*32 + (lane>>4)*8 + j
  for (int i = tid; i < 768 * 256; i += stride) {
    const int j = i & 7, ln = (i >> 3) & 63, kc = (i >> 9) & 7, t12 = i >> 12;
    const int tt = t12 % 6, wvv = t12 / 6;
    const int n = (tt >> 1) * 256 + 32 * wvv + (tt & 1) * 16 + (ln & 15);
    const int k = kc * 32 + (ln >> 4) * 8 + j;
    WhhFrag[i] = f2bf(W_hh[n * 256 + k]);
  }
}

// ---------------------------------------------------------------------------
// GEMM (B^T form): C[m,n] = sum_k A[m,k]*B[n,k] (+bias1[n] (+bias2[n] if n<lim))
// bf16 inputs, f32 accum; 128x128 tile, BK=64, 4 waves, double-buffered LDS,
// global_load_lds staging (m97 structure).
// OMODE: 0 = f32 linear, 1 = bf16 linear, 2 = bf16 gi pair-packed
//        [m][j][tp][{r,z,n,pad}]  (j = (c>>5)*16 + (c&15), tp = (c>>4)&1)
// ---------------------------------------------------------------------------
template <int OMODE>
__global__ __launch_bounds__(256) void fpp_gemm_bt(
    const short* __restrict__ A, const short* __restrict__ B, void* __restrict__ C,
    const float* __restrict__ bias1, const float* __restrict__ bias2, int bias2_limit,
    int M, int N, int K, int ldc, int MT, int NT, int SUPER) {
  // m-supertile mapping: SUPER consecutive m-tiles share the whole B panel in L2
  const int bid = blockIdx.x;
  const int per_super = SUPER * NT;
  const int srow = bid / per_super;
  const int rrem = bid - srow * per_super;
  const int mi = srow * SUPER + (rrem % SUPER);
  const int ni = rrem / SUPER;
  const int m0 = mi * 128, n0 = ni * 128;

  __shared__ __attribute__((aligned(16))) short As[2][128 * 64];
  __shared__ __attribute__((aligned(16))) short Bs[2][128 * 64];

  const int tid = threadIdx.x;
  const int lane = tid & 63;
  const int wv = tid >> 6;
  const int wr = wv >> 1, wc = wv & 1;

  f32x4 acc[4][4];
#pragma unroll
  for (int a_ = 0; a_ < 4; ++a_)
#pragma unroll
    for (int b_ = 0; b_ < 4; ++b_) acc[a_][b_] = f32x4{0.f, 0.f, 0.f, 0.f};

  auto stage = [&](int buf, int k0) {
#pragma unroll
    for (int c = 0; c < 4; ++c) {
      const int chunk = c * 256 + tid;        // 16B chunk id
      const int row = chunk >> 3, kc8 = chunk & 7;
      int gr = m0 + row; gr = (gr < M) ? gr : (M - 1);
      gload_lds16(A + (int64_t)gr * K + k0 + kc8 * 8,
                  (char*)&As[buf][0] + (c * 256 + wv * 64) * 16);
    }
#pragma unroll
    for (int c = 0; c < 4; ++c) {
      const int chunk = c * 256 + tid;
      const int row = chunk >> 3, kc8 = chunk & 7;
      int gn = n0 + row; gn = (gn < N) ? gn : (N - 1);
      gload_lds16(B + (int64_t)gn * K + k0 + kc8 * 8,
                  (char*)&Bs[buf][0] + (c * 256 + wv * 64) * 16);
    }
  };

  const int nk = K >> 6;
  stage(0, 0);
  asm volatile("s_waitcnt vmcnt(0)" ::: "memory");
  __syncthreads();
  for (int ks = 0; ks < nk; ++ks) {
    const int cur = ks & 1;
    if (ks + 1 < nk) stage(cur ^ 1, (ks + 1) << 6);  // async prefetch next K-tile
#pragma unroll
    for (int kk = 0; kk < 2; ++kk) {
      bf16x8 af[4], bfr[4];
#pragma unroll
      for (int mt = 0; mt < 4; ++mt)
        af[mt] = *(const bf16x8*)&As[cur][(wr * 64 + mt * 16 + (lane & 15)) * 64 +
                                          kk * 32 + (lane >> 4) * 8];
#pragma unroll
      for (int nt = 0; nt < 4; ++nt)
        bfr[nt] = *(const bf16x8*)&Bs[cur][(wc * 64 + nt * 16 + (lane & 15)) * 64 +
                                           kk * 32 + (lane >> 4) * 8];
#pragma unroll
      for (int mt = 0; mt < 4; ++mt)
#pragma unroll
        for (int nt = 0; nt < 4; ++nt)
          acc[mt][nt] = __builtin_amdgcn_mfma_f32_16x16x32_bf16(
              af[mt], bfr[nt], acc[mt][nt], 0, 0, 0);
    }
    asm volatile("s_waitcnt vmcnt(0)" ::: "memory");
    __syncthreads();
  }

  // epilogue: D layout row=(lane>>4)*4+r (M dim), col=lane&15 (N dim)
#pragma unroll
  for (int nt = 0; nt < 4; ++nt) {
    const int col = n0 + wc * 64 + nt * 16 + (lane & 15);
    if (col >= N) continue;
    float badd = 0.f;
    if (bias1) badd += bias1[col];
    if (bias2 && col < bias2_limit) badd += bias2[col];
#pragma unroll
    for (int mt = 0; mt < 4; ++mt) {
      const int rbase = m0 + wr * 64 + mt * 16 + (lane >> 4) * 4;
#pragma unroll
      for (int r = 0; r < 4; ++r) {
        const int row = rbase + r;
        if (row < M) {
          const float v = acc[mt][nt][r] + badd;
          if (OMODE == 0)
            ((float*)C)[(int64_t)row * ldc + col] = v;
          else if (OMODE == 1)
            ((short*)C)[(int64_t)row * ldc + col] = f2bf(v);
          else {
            // pair-packed: c = col&255, gate = col>>8
            const int cc = col & 255;
            const int jj = ((cc >> 5) << 4) + (cc & 15);
            ((short*)C)[(int64_t)row * 1024 + jj * 8 + ((cc >> 4) & 1) * 4 +
                        (col >> 8)] = f2bf(v);
          }
        }
      }
    }
  }
}

// ---------------------------------------------------------------------------
// GRU: 4 blocks x 16 users x 8 waves. ONE barrier per step:
//  - h double-buffered in LDS: MFMA(s) reads h[s&1], gates(s) write h[(s+1)&1]
//    -> no barrier between MFMA and gate phases; wave i's gate (VALU/trans)
//    overlaps wave j's MFMA on the same SIMD.
//  - gi triple-buffered: stage gi(s+2) at top of step s (2 steps of latency
//    margin); end-of-step blob s_waitcnt vmcnt(12) lgkmcnt(0); s_barrier keeps
//    [L4(next), S8(cur)] in flight. Buffer b: written at steps == b+1 (mod 3),
//    read at steps == b (mod 3); one barrier between -> race-free.
// Plain __builtin MFMAs (compiler handles hazards; fastest variant measured).
// ---------------------------------------------------------------------------
__global__ __attribute__((amdgpu_waves_per_eu(2, 2))) __launch_bounds__(512)
void fpp_gru(
    const int* __restrict__ x, const float* __restrict__ h0,
    const short* __restrict__ WhhFrag, const float* __restrict__ b_hh,
    const short* __restrict__ giV, float* __restrict__ out,
    float* __restrict__ hlast) {
  __shared__ __attribute__((aligned(16))) short h_lds[2][16 * 264];     // 16.9 KB
  __shared__ __attribute__((aligned(16))) short gi_lds[3][16 * 1024];   // 96 KB
  __shared__ __attribute__((aligned(16))) uint16_t x_lds[256 * 16];     // 8 KB

  const int tid = threadIdx.x;
  const int lane = tid & 63;
  const int wv = tid >> 6;  // wave 0..7
  const int u0 = blockIdx.x * 16;
  const int g = lane >> 4;
  const int lo = lane & 15;

  for (int i = tid; i < 256 * 16; i += 512)
    x_lds[i] = (uint16_t)x[(i >> 4) * 64 + u0 + (i & 15)];

  // preload W_hh B-fragments: 48 coalesced dwordx4 loads (fragment-linear)
  bf16x8 Wf[6][8];
  {
    const bf16x8* wfp = (const bf16x8*)WhhFrag;
#pragma unroll
    for (int tt = 0; tt < 6; ++tt)
#pragma unroll
      for (int kc = 0; kc < 8; ++kc)
        Wf[tt][kc] = wfp[((wv * 6 + tt) * 8 + kc) * 64 + lane];
  }
  // b_hh for n-gate (r/z parts folded into giV)
  const float bhh0 = b_hh[512 + 32 * wv + lo];
  const float bhh1 = b_hh[512 + 32 * wv + 16 + lo];

  // h cells owned by this lane: u = g*4+r, c = 32w + tp*16 + lo
  float hreg[2][4];
#pragma unroll
  for (int tp = 0; tp < 2; ++tp)
#pragma unroll
    for (int r = 0; r < 4; ++r) {
      const int u = g * 4 + r, c = 32 * wv + tp * 16 + lo;
      const float v = h0[(u0 + u) * 256 + c];
      hreg[tp][r] = v;
      h_lds[0][u * 264 + c] = f2bf(v);
    }
  __syncthreads();  // x_lds + h_lds[0] visible before any stage/MFMA

  // stage gi rows (pair-packed, 2KB/user) for step row ss into LDS dst
  auto stage_gi = [&](short* dst, int ss) {
    const int xid0 = x_lds[ss * 16 + 2 * wv];
    const int xid1 = x_lds[ss * 16 + 2 * wv + 1];
#pragma unroll
    for (int c = 0; c < 4; ++c) {
      const int p = c * 64 + lane;     // chunk 0..255 over the 2-row region
      const int xid = (p >= 128) ? xid1 : xid0;
      const int pin = p & 127;         // 16B chunk within row
      gload_lds16(giV + (int64_t)xid * 1024 + pin * 8,
                  (char*)dst + wv * 4096 + c * 1024);
    }
  };

  short* gb0 = gi_lds[0];  // read buffer for current step
  short* gb1 = gi_lds[1];  // next step's (already drained 1 step early)
  short* gb2 = gi_lds[2];  // write buffer (staged this step for s+2)
  const short* hr = h_lds[0];  // MFMA reads
  short* hw = h_lds[1];        // gates write

  stage_gi(gb0, 0);
  stage_gi(gb1, 1);
  asm volatile("s_waitcnt vmcnt(0) lgkmcnt(0)\n\ts_barrier" ::: "memory");

  for (int s = 0; s < 256; ++s) {
    // stage gi(s+2) into the rotating write buffer (wrapped row at the tail:
    // harmless, keeps the VM queue shape uniform for the vmcnt(12) proof)
    stage_gi(gb2, (s + 2) & 255);

    // gh = h @ W_hh^T : 48 MFMAs off h_lds[s&1]; n-gate accs seeded with b_hh
    f32x4 acc[6];
#pragma unroll
    for (int tt = 0; tt < 4; ++tt) acc[tt] = f32x4{0.f, 0.f, 0.f, 0.f};
    acc[4] = f32x4{bhh0, bhh0, bhh0, bhh0};
    acc[5] = f32x4{bhh1, bhh1, bhh1, bhh1};
#pragma unroll
    for (int kc = 0; kc < 8; ++kc) {
      const bf16x8 a = *(const bf16x8*)&hr[lo * 264 + kc * 32 + g * 8];
#pragma unroll
      for (int tt = 0; tt < 6; ++tt)
        acc[tt] = __builtin_amdgcn_mfma_f32_16x16x32_bf16(a, Wf[tt][kc], acc[tt], 0, 0, 0);
    }

    // gates immediately (no barrier: gi[s%3] was drained at the END of step
    // s-1 and made visible by that barrier; h write target is the OTHER buf)
#pragma unroll
    for (int r = 0; r < 4; ++r) {
      const int u = g * 4 + r;
      const bf16x8 gv = *(const bf16x8*)((const char*)gb0 + u * 2048 + (wv * 16 + lo) * 16);
#pragma unroll
      for (int tp = 0; tp < 2; ++tp) {
        const int c = 32 * wv + tp * 16 + lo;
        const float gir = bf2f(gv[tp * 4 + 0]);
        const float giz = bf2f(gv[tp * 4 + 1]);
        const float gin = bf2f(gv[tp * 4 + 2]);
        const float xr = acc[0 + tp][r] + gir;
        const float rr = __builtin_amdgcn_rcpf(1.f + __builtin_amdgcn_exp2f(-1.4426950408889634f * xr));
        const float xz = acc[2 + tp][r] + giz;
        const float zz = __builtin_amdgcn_rcpf(1.f + __builtin_amdgcn_exp2f(-1.4426950408889634f * xz));
        float xn = gin + rr * acc[4 + tp][r];
        xn = fminf(fmaxf(xn, -12.f), 12.f);
        const float E = __builtin_amdgcn_exp2f(2.8853900817779268f * xn);
        const float nn = (E - 1.f) * __builtin_amdgcn_rcpf(E + 1.f);
        const float hv = nn + zz * (hreg[tp][r] - nn);
        hreg[tp][r] = hv;
        hw[u * 264 + c] = f2bf(hv);
        out[((int64_t)s * 64 + u0 + u) * 256 + c] = hv;  // store NOT awaited
      }
    }

    // single end-of-step barrier: drain [gi(s+2) issued LAST step? no --
    // drains the two oldest groups: L4(gi s+2 from step s? see proof) keeps
    // [L4(just issued), S8(this step)] = 12 in flight.
    asm volatile(
        "s_waitcnt vmcnt(12) lgkmcnt(0)\n\t"
        "s_barrier" ::: "memory");

    // rotate gi buffers; swap h buffers
    short* tg = gb0; gb0 = gb1; gb1 = gb2; gb2 = tg;
    short* th = (short*)hr; hr = hw; hw = th;
  }

#pragma unroll
  for (int tp = 0; tp < 2; ++tp)
#pragma unroll
    for (int r = 0; r < 4; ++r) {
      const int u = g * 4 + r, c = 32 * wv + tp * 16 + lo;
      hlast[(u0 + u) * 256 + c] = hreg[tp][r];
    }
}

// ---------------------------------------------------------------------------
// attention: per (u, i-block of 64): loop causal j-blocks; w in LDS; weighted
// sum of GRU hiddens; writes bf16 into A2[:, 0:256]. f32 vector math.
// ---------------------------------------------------------------------------
__global__ __launch_bounds__(256) void fpp_attn(
    const float* __restrict__ t_g, const float* __restrict__ s_g,
    const float* __restrict__ gout, short* __restrict__ A2) {
  const int u = blockIdx.x;   // 0..63
  const int ib = blockIdx.y;  // 0..3
  const int tid = threadIdx.x;
  const int iloc = tid >> 2;  // 0..63
  const int q = tid & 3;      // h quarter (64 each)

  __shared__ __attribute__((aligned(16))) float out_lds[64][272];  // q-seg stride 68
  __shared__ __attribute__((aligned(16))) float w_lds[64][65];
  __shared__ float ti[64], si0[64], si1[64], tj[64], sj0[64], sj1[64], sum_lds[64];

  if (tid < 64) {
    const int ig = ib * 64 + tid;
    ti[tid] = t_g[ig * 64 + u];
    si0[tid] = s_g[(ig * 64 + u) * 2 + 0];
    si1[tid] = s_g[(ig * 64 + u) * 2 + 1];
    sum_lds[tid] = 0.f;
  }

  f32x4 accv[16];
#pragma unroll
  for (int hh = 0; hh < 16; ++hh) accv[hh] = f32x4{0.f, 0.f, 0.f, 0.f};

  const int igl = ib * 64 + iloc;

  for (int jb = 0; jb <= ib; ++jb) {
    __syncthreads();  // protect LDS vs previous iteration readers
    {
      const int jj = tid >> 2;
      const float* src = gout + ((int64_t)(jb * 64 + jj) * 64 + u) * 256 + q * 64;
#pragma unroll
      for (int hh = 0; hh < 16; ++hh)
        *(f32x4*)&out_lds[jj][q * 68 + hh * 4] = *(const f32x4*)(src + hh * 4);
    }
    if (tid < 64) {
      const int jg = jb * 64 + tid;
      tj[tid] = t_g[jg * 64 + u];
      sj0[tid] = s_g[(jg * 64 + u) * 2 + 0];
      sj1[tid] = s_g[(jg * 64 + u) * 2 + 1];
    }
    __syncthreads();
    {
      const float tiv = ti[iloc], p0 = si0[iloc], p1 = si1[iloc];
#pragma unroll
      for (int jj = 0; jj < 16; ++jj) {
        const int j = q * 16 + jj;
        const int jgl = jb * 64 + j;
        const float dt = tiv - tj[j];
        // f_t = (cos(2*pi*dt)+1)*0.5*exp(-0.1*dt); v_cos takes revolutions
        const float ft = (__builtin_amdgcn_cosf(dt) + 1.f) * 0.5f *
                         __builtin_amdgcn_exp2f(-0.14426950408889634f * dt);
        const float dx = p0 - sj0[j], dy = p1 - sj1[j];
        const float ds = __builtin_amdgcn_sqrtf(dx * dx + dy * dy);
        const float fs = __builtin_amdgcn_exp2f(-144.26950408889634f * ds);
        float wvv = ft * fs + 1e-10f;
        if (jgl > igl) wvv = 0.f;  // causal
        w_lds[iloc][j] = wvv;
      }
    }
    __syncthreads();
    if (tid < 64) {
      float sm = 0.f;
#pragma unroll
      for (int j = 0; j < 64; ++j) sm += w_lds[tid][j];
      sum_lds[tid] += sm;
    }
    for (int j = 0; j < 64; ++j) {
      const float wvv = w_lds[iloc][j];
#pragma unroll
      for (int hh = 0; hh < 16; ++hh) {
        const f32x4 o = *(const f32x4*)&out_lds[j][q * 68 + hh * 4];
        accv[hh] += o * wvv;
      }
    }
  }
  __syncthreads();
  const float inv = 1.f / sum_lds[iloc];
  short* dst = A2 + (int64_t)((ib * 64 + iloc) * 64 + u) * 512 + q * 64;
#pragma unroll
  for (int hh = 0; hh < 16; ++hh) {
    const f32x4 v = accv[hh] * inv;
    short4 sv;
    sv.x = f2bf(v[0]); sv.y = f2bf(v[1]); sv.z = f2bf(v[2]); sv.w = f2bf(v[3]);
    *(short4*)(dst + hh * 4) = sv;
  }
}

// ---------------------------------------------------------------------------
extern "C" void kernel_launch(void* const* d_in, const int* in_sizes, int n_in,
                              void* d_out, int out_size, void* d_ws, size_t ws_size,
                              hipStream_t stream) {
  (void)in_sizes; (void)n_in; (void)out_size; (void)ws_size;
  const int*   x      = (const int*)  d_in[0];
  const float* t      = (const float*)d_in[1];
  const float* s      = (const float*)d_in[2];
  // d_in[3], d_in[4] (y_t, y_s) unused by reference
  const float* h0     = (const float*)d_in[5];
  const int*   au     = (const int*)  d_in[6];
  const float* enc_W  = (const float*)d_in[7];
  const float* user_W = (const float*)d_in[8];
  const float* W_ih   = (const float*)d_in[9];
  const float* W_hh   = (const float*)d_in[10];
  const float* b_ih   = (const float*)d_in[11];
  const float* b_hh   = (const float*)d_in[12];
  const float* fc_W   = (const float*)d_in[13];
  const float* fc_b   = (const float*)d_in[14];

  float* y = (float*)d_out;
  float* hlast = y + Y_ELEMS;

  char* ws = (char*)d_ws;
  short* giV   = (short*)(ws + 0);          // 10000x256x4 bf16, pair-packed
  short* A2    = (short*)(ws + 20480000);   // 16384x512 bf16
  short* fcWb  = (short*)(ws + 37257216);   // 10000x512 bf16
  short* encWb = (short*)(ws + 47497216);   // 10000x256 bf16
  short* WihB  = (short*)(ws + 52617216);   // 768x256 bf16
  float* gout  = (float*)(ws + 53010432);   // 256x64x256 f32 GRU hiddens
  // WhhFrag scratch lives inside d_out's y region (written by prep, read by
  // GRU, overwritten by the final GEMM) to avoid growing ws usage.
  short* WhhFrag = (short*)(y + 80000000);  // 768x256 bf16, fragment-linear

  fpp_prep<<<1024, 256, 0, stream>>>(enc_W, W_ih, fc_W, user_W, W_hh, au,
                                     encWb, WihB, fcWb, A2, WhhFrag);
  // giV = enc_W @ W_ih.T + b_ih (+ b_hh for n<512); bf16, pair-packed layout
  fpp_gemm_bt<2><<<79 * 6, 256, 0, stream>>>(encWb, WihB, giV, b_ih, b_hh, 512,
                                             10000, 768, 256, 0, 79, 6, 1);
  fpp_gru<<<4, 512, 0, stream>>>(x, h0, WhhFrag, b_hh, giV, gout, hlast);
  fpp_attn<<<dim3(64, 4), 256, 0, stream>>>(t, s, gout, A2);
  // y = A2 @ fc_W.T + fc_b ; f32 out
  fpp_gemm_bt<0><<<128 * 79, 256, 0, stream>>>(A2, fcWb, y, fc_b, nullptr, 0,
                                               16384, 10000, 512, 10000, 128, 79, 8);
}

// Round 10
// 916.299 us; speedup vs baseline: 1.4184x; 1.3509x over previous
//
#include <hip/hip_runtime.h>
#include <stdint.h>

// FlashbackPlusPlus: embed->GRU->spatiotemporal causal attention->FC
// S=256 U=64 H=256 V=10000
#define S_LEN 256
#define U_LEN 64
#define H_DIM 256
#define V_DIM 10000
#define Y_ELEMS 163840000LL  // S*U*V

typedef short bf16x8 __attribute__((ext_vector_type(8)));
typedef float f32x4 __attribute__((ext_vector_type(4)));

__device__ __forceinline__ short f2bf(float f) {
  union { float f; uint32_t u; } v; v.f = f;
  uint32_t r = v.u + 0x7FFFu + ((v.u >> 16) & 1u);  // RNE
  return (short)(r >> 16);
}
__device__ __forceinline__ float bf2f(short s) {
  union { uint32_t u; float f; } v; v.u = ((uint32_t)(uint16_t)s) << 16;
  return v.f;
}

// global -> LDS async copy, 16B per lane. LDS dest = wave-uniform base + lane*16.
__device__ __forceinline__ void gload_lds16(const void* g, void* l) {
  __builtin_amdgcn_global_load_lds(
      (const __attribute__((address_space(1))) char*)(uintptr_t)g,
      (__attribute__((address_space(3))) char*)(uintptr_t)l, 16, 0, 0);
}

// ---------------------------------------------------------------------------
// prep: f32->bf16 weight conversions + A2 user-embedding half + W_hh fragment
// pack (fragment-linear so the GRU preamble is 48 coalesced dwordx4 loads).
// ---------------------------------------------------------------------------
__global__ __launch_bounds__(256) void fpp_prep(
    const float* __restrict__ enc_W, const float* __restrict__ W_ih,
    const float* __restrict__ fc_W, const float* __restrict__ user_W,
    const float* __restrict__ W_hh, const int* __restrict__ active_user,
    short* __restrict__ encWb, short* __restrict__ WihB,
    short* __restrict__ fcWb, short* __restrict__ A2,
    short* __restrict__ WhhFrag) {
  const int tid = blockIdx.x * 256 + threadIdx.x;
  const int stride = gridDim.x * 256;
  for (int i = tid; i < V_DIM * H_DIM; i += stride) encWb[i] = f2bf(enc_W[i]);
  for (int i = tid; i < 3 * H_DIM * H_DIM; i += stride) WihB[i] = f2bf(W_ih[i]);
  for (int i = tid; i < V_DIM * 2 * H_DIM; i += stride) fcWb[i] = f2bf(fc_W[i]);
  // A2 rows r = s*64+u ; cols [256,512) = user_W[active_user[u]]
  for (int i = tid; i < 16384 * 256; i += stride) {
    const int row = i >> 8, k = i & 255;
    const int au = active_user[row & 63];
    A2[(int64_t)row * 512 + 256 + k] = f2bf(user_W[(int64_t)au * 256 + k]);
  }
  // WhhFrag[i], i = (((wv*6+tt)*8+kc)*64+lane)*8+j ; holds W_hh[n][k] bf16 with
  // n = (tt>>1)*256 + 32*wv + (tt&1)*16 + (lane&15), k = kc*32 + (lane>>4)*8 + j
  for (int i = tid; i < 768 * 256; i += stride) {
    const int j = i & 7, ln = (i >> 3) & 63, kc = (i >> 9) & 7, t12 = i >> 12;
    const int tt = t12 % 6, wvv = t12 / 6;
    const int n = (tt >> 1) * 256 + 32 * wvv + (tt & 1) * 16 + (ln & 15);
    const int k = kc * 32 + (ln >> 4) * 8 + j;
    WhhFrag[i] = f2bf(W_hh[n * 256 + k]);
  }
}

// ---------------------------------------------------------------------------
// GEMM (B^T form): C[m,n] = sum_k A[m,k]*B[n,k] (+bias1[n] (+bias2[n] if n<lim))
// bf16 inputs, f32 accum; 128x128 tile, BK=64, 4 waves, double-buffered LDS,
// global_load_lds staging (m97 structure).
// OMODE: 0 = f32 linear, 1 = bf16 linear, 2 = bf16 gi pair-packed
//        [m][j][tp][{r,z,n,pad}]  (j = (c>>5)*16 + (c&15), tp = (c>>4)&1)
// ---------------------------------------------------------------------------
template <int OMODE>
__global__ __launch_bounds__(256) void fpp_gemm_bt(
    const short* __restrict__ A, const short* __restrict__ B, void* __restrict__ C,
    const float* __restrict__ bias1, const float* __restrict__ bias2, int bias2_limit,
    int M, int N, int K, int ldc, int MT, int NT, int SUPER) {
  // m-supertile mapping: SUPER consecutive m-tiles share the whole B panel in L2
  const int bid = blockIdx.x;
  const int per_super = SUPER * NT;
  const int srow = bid / per_super;
  const int rrem = bid - srow * per_super;
  const int mi = srow * SUPER + (rrem % SUPER);
  const int ni = rrem / SUPER;
  const int m0 = mi * 128, n0 = ni * 128;

  __shared__ __attribute__((aligned(16))) short As[2][128 * 64];
  __shared__ __attribute__((aligned(16))) short Bs[2][128 * 64];

  const int tid = threadIdx.x;
  const int lane = tid & 63;
  const int wv = tid >> 6;
  const int wr = wv >> 1, wc = wv & 1;

  f32x4 acc[4][4];
#pragma unroll
  for (int a_ = 0; a_ < 4; ++a_)
#pragma unroll
    for (int b_ = 0; b_ < 4; ++b_) acc[a_][b_] = f32x4{0.f, 0.f, 0.f, 0.f};

  auto stage = [&](int buf, int k0) {
#pragma unroll
    for (int c = 0; c < 4; ++c) {
      const int chunk = c * 256 + tid;        // 16B chunk id
      const int row = chunk >> 3, kc8 = chunk & 7;
      int gr = m0 + row; gr = (gr < M) ? gr : (M - 1);
      gload_lds16(A + (int64_t)gr * K + k0 + kc8 * 8,
                  (char*)&As[buf][0] + (c * 256 + wv * 64) * 16);
    }
#pragma unroll
    for (int c = 0; c < 4; ++c) {
      const int chunk = c * 256 + tid;
      const int row = chunk >> 3, kc8 = chunk & 7;
      int gn = n0 + row; gn = (gn < N) ? gn : (N - 1);
      gload_lds16(B + (int64_t)gn * K + k0 + kc8 * 8,
                  (char*)&Bs[buf][0] + (c * 256 + wv * 64) * 16);
    }
  };

  const int nk = K >> 6;
  stage(0, 0);
  asm volatile("s_waitcnt vmcnt(0)" ::: "memory");
  __syncthreads();
  for (int ks = 0; ks < nk; ++ks) {
    const int cur = ks & 1;
    if (ks + 1 < nk) stage(cur ^ 1, (ks + 1) << 6);  // async prefetch next K-tile
#pragma unroll
    for (int kk = 0; kk < 2; ++kk) {
      bf16x8 af[4], bfr[4];
#pragma unroll
      for (int mt = 0; mt < 4; ++mt)
        af[mt] = *(const bf16x8*)&As[cur][(wr * 64 + mt * 16 + (lane & 15)) * 64 +
                                          kk * 32 + (lane >> 4) * 8];
#pragma unroll
      for (int nt = 0; nt < 4; ++nt)
        bfr[nt] = *(const bf16x8*)&Bs[cur][(wc * 64 + nt * 16 + (lane & 15)) * 64 +
                                           kk * 32 + (lane >> 4) * 8];
#pragma unroll
      for (int mt = 0; mt < 4; ++mt)
#pragma unroll
        for (int nt = 0; nt < 4; ++nt)
          acc[mt][nt] = __builtin_amdgcn_mfma_f32_16x16x32_bf16(
              af[mt], bfr[nt], acc[mt][nt], 0, 0, 0);
    }
    asm volatile("s_waitcnt vmcnt(0)" ::: "memory");
    __syncthreads();
  }

  // epilogue: D layout row=(lane>>4)*4+r (M dim), col=lane&15 (N dim)
#pragma unroll
  for (int nt = 0; nt < 4; ++nt) {
    const int col = n0 + wc * 64 + nt * 16 + (lane & 15);
    if (col >= N) continue;
    float badd = 0.f;
    if (bias1) badd += bias1[col];
    if (bias2 && col < bias2_limit) badd += bias2[col];
#pragma unroll
    for (int mt = 0; mt < 4; ++mt) {
      const int rbase = m0 + wr * 64 + mt * 16 + (lane >> 4) * 4;
#pragma unroll
      for (int r = 0; r < 4; ++r) {
        const int row = rbase + r;
        if (row < M) {
          const float v = acc[mt][nt][r] + badd;
          if (OMODE == 0)
            ((float*)C)[(int64_t)row * ldc + col] = v;
          else if (OMODE == 1)
            ((short*)C)[(int64_t)row * ldc + col] = f2bf(v);
          else {
            // pair-packed: c = col&255, gate = col>>8
            const int cc = col & 255;
            const int jj = ((cc >> 5) << 4) + (cc & 15);
            ((short*)C)[(int64_t)row * 1024 + jj * 8 + ((cc >> 4) & 1) * 4 +
                        (col >> 8)] = f2bf(v);
          }
        }
      }
    }
  }
}

// ---------------------------------------------------------------------------
// GRU v2: 8 blocks x 8 users x 8 waves (8 CUs). Non-MFMA work per CU halves:
//  - D-rows 0-7 (lanes<32) hold the 8 users; odd (tp=1) acc tiles are swapped
//    to lanes>=32 via __shfl_xor(.,32) so ALL lanes process 4 gate cells each
//    (gate instruction stream per wave halves).
//  - gi: per-lane register prefetch (4 x dwordx2 gathers, 1 step ahead) -- no
//    gi LDS at all; compiler inserts the vmcnt before first use.
//  - h double-buffered in LDS (rows 8-15 zeroed once -> D rows 8-15 = 0);
//    ONE lgkmcnt(0)+s_barrier per step (R9 proof).
// ---------------------------------------------------------------------------
__global__ __attribute__((amdgpu_waves_per_eu(2, 2))) __launch_bounds__(512)
void fpp_gru(
    const int* __restrict__ x, const float* __restrict__ h0,
    const short* __restrict__ WhhFrag, const float* __restrict__ b_hh,
    const short* __restrict__ giV, float* __restrict__ out,
    float* __restrict__ hlast) {
  __shared__ __attribute__((aligned(16))) short h_lds[2][16 * 264];  // 16.9 KB
  __shared__ __attribute__((aligned(16))) uint16_t x_lds[256 * 8];   // 4 KB

  const int tid = threadIdx.x;
  const int lane = tid & 63;
  const int wv = tid >> 6;  // wave 0..7
  const int u0 = blockIdx.x * 8;
  const int g = lane >> 4;
  const int lo = lane & 15;
  const int tp = (lane >= 32) ? 1 : 0;  // which 16-col half this lane gates
  const int uh = g & 1;                 // user-half selector: u = uh*4 + r

  for (int i = tid; i < 256 * 8; i += 512)
    x_lds[i] = (uint16_t)x[(i >> 3) * 64 + u0 + (i & 7)];
  // zero h rows 8-15 (both buffers): A-operand rows for nonexistent users
  for (int i = tid; i < 8 * 264; i += 512) {
    h_lds[0][8 * 264 + i] = 0;
    h_lds[1][8 * 264 + i] = 0;
  }

  // preload W_hh B-fragments: 48 coalesced dwordx4 loads (fragment-linear)
  bf16x8 Wf[6][8];
  {
    const bf16x8* wfp = (const bf16x8*)WhhFrag;
#pragma unroll
    for (int tt = 0; tt < 6; ++tt)
#pragma unroll
      for (int kc = 0; kc < 8; ++kc)
        Wf[tt][kc] = wfp[((wv * 6 + tt) * 8 + kc) * 64 + lane];
  }
  // n-gate b_hh for this lane's single column c = 32wv + tp*16 + lo
  const float bhh = b_hh[512 + 32 * wv + tp * 16 + lo];

  // 4 cells per lane: u = uh*4+r, c = 32wv + tp*16 + lo
  const int c_own = 32 * wv + tp * 16 + lo;
  float hreg[4];
#pragma unroll
  for (int r = 0; r < 4; ++r) {
    const int u = uh * 4 + r;
    const float v = h0[(u0 + u) * 256 + c_own];
    hreg[r] = v;
    h_lds[0][u * 264 + c_own] = f2bf(v);
  }

  // gi register prefetch: per lane, 4 x 8B (gates r,z,n for (u, c_own))
  typedef unsigned int uint2v __attribute__((ext_vector_type(2)));
  auto load_gi = [&](uint2v* dst, int ss) {
#pragma unroll
    for (int r = 0; r < 4; ++r) {
      const int u = uh * 4 + r;
      const int xid = x_lds[ss * 8 + u];
      dst[r] = *(const uint2v*)((const char*)giV + (int64_t)xid * 2048 +
                                (wv * 16 + lo) * 16 + tp * 8);
    }
  };

  __syncthreads();  // x_lds + h_lds[0] + zeroed rows visible

  uint2v gcur[4], gnx[4];
  load_gi(gcur, 0);

  for (int s = 0; s < 256; ++s) {
    load_gi(gnx, (s + 1) & 255);  // prefetch next step (wrapped tail: unused)

    const short* hr = h_lds[s & 1];
    short* hw = h_lds[(s + 1) & 1];

    // gh = h @ W_hh^T : 48 MFMAs; D rows 8-15 are zero (A rows zeroed)
    f32x4 acc[6];
#pragma unroll
    for (int tt = 0; tt < 6; ++tt) acc[tt] = f32x4{0.f, 0.f, 0.f, 0.f};
#pragma unroll
    for (int kc = 0; kc < 8; ++kc) {
      const bf16x8 a = *(const bf16x8*)&hr[lo * 264 + kc * 32 + g * 8];
#pragma unroll
      for (int tt = 0; tt < 6; ++tt)
        acc[tt] = __builtin_amdgcn_mfma_f32_16x16x32_bf16(a, Wf[tt][kc], acc[tt], 0, 0, 0);
    }

    // tp-split: odd tiles (tp=1) of lanes<32 -> lanes>=32 via shfl_xor(32).
    // mine[G][r] = gh for gate G at this lane's (u, c_own).
    float mine[3][4];
#pragma unroll
    for (int G = 0; G < 3; ++G) {
#pragma unroll
      for (int r = 0; r < 4; ++r) {
        const float swv = __shfl_xor(acc[2 * G + 1][r], 32, 64);
        mine[G][r] = (lane < 32) ? acc[2 * G][r] : swv;
      }
    }

    // gates: 4 cells per lane
#pragma unroll
    for (int r = 0; r < 4; ++r) {
      const int u = uh * 4 + r;
      const short4 gv = *(const short4*)&gcur[r];
      const float gir = bf2f(gv.x);
      const float giz = bf2f(gv.y);
      const float gin = bf2f(gv.z);
      const float xr = mine[0][r] + gir;
      const float rr = __builtin_amdgcn_rcpf(1.f + __builtin_amdgcn_exp2f(-1.4426950408889634f * xr));
      const float xz = mine[1][r] + giz;
      const float zz = __builtin_amdgcn_rcpf(1.f + __builtin_amdgcn_exp2f(-1.4426950408889634f * xz));
      float xn = gin + rr * (mine[2][r] + bhh);
      xn = fminf(fmaxf(xn, -12.f), 12.f);
      const float E = __builtin_amdgcn_exp2f(2.8853900817779268f * xn);
      const float nn = (E - 1.f) * __builtin_amdgcn_rcpf(E + 1.f);
      const float hv = nn + zz * (hreg[r] - nn);
      hreg[r] = hv;
      hw[u * 264 + c_own] = f2bf(hv);
      out[((int64_t)s * 64 + u0 + u) * 256 + c_own] = hv;  // store not awaited
    }

    // single per-step barrier: h writes visible; vm ops stay in flight
    asm volatile("s_waitcnt lgkmcnt(0)\n\ts_barrier" ::: "memory");

#pragma unroll
    for (int r = 0; r < 4; ++r) gcur[r] = gnx[r];
  }

#pragma unroll
  for (int r = 0; r < 4; ++r) {
    const int u = uh * 4 + r;
    hlast[(u0 + u) * 256 + c_own] = hreg[r];
  }
}

// ---------------------------------------------------------------------------
// attention: per (u, i-block of 64): loop causal j-blocks; w in LDS; weighted
// sum of GRU hiddens; writes bf16 into A2[:, 0:256]. f32 vector math.
// ---------------------------------------------------------------------------
__global__ __launch_bounds__(256) void fpp_attn(
    const float* __restrict__ t_g, const float* __restrict__ s_g,
    const float* __restrict__ gout, short* __restrict__ A2) {
  const int u = blockIdx.x;   // 0..63
  const int ib = blockIdx.y;  // 0..3
  const int tid = threadIdx.x;
  const int iloc = tid >> 2;  // 0..63
  const int q = tid & 3;      // h quarter (64 each)

  __shared__ __attribute__((aligned(16))) float out_lds[64][272];  // q-seg stride 68
  __shared__ __attribute__((aligned(16))) float w_lds[64][65];
  __shared__ float ti[64], si0[64], si1[64], tj[64], sj0[64], sj1[64], sum_lds[64];

  if (tid < 64) {
    const int ig = ib * 64 + tid;
    ti[tid] = t_g[ig * 64 + u];
    si0[tid] = s_g[(ig * 64 + u) * 2 + 0];
    si1[tid] = s_g[(ig * 64 + u) * 2 + 1];
    sum_lds[tid] = 0.f;
  }

  f32x4 accv[16];
#pragma unroll
  for (int hh = 0; hh < 16; ++hh) accv[hh] = f32x4{0.f, 0.f, 0.f, 0.f};

  const int igl = ib * 64 + iloc;

  for (int jb = 0; jb <= ib; ++jb) {
    __syncthreads();  // protect LDS vs previous iteration readers
    {
      const int jj = tid >> 2;
      const float* src = gout + ((int64_t)(jb * 64 + jj) * 64 + u) * 256 + q * 64;
#pragma unroll
      for (int hh = 0; hh < 16; ++hh)
        *(f32x4*)&out_lds[jj][q * 68 + hh * 4] = *(const f32x4*)(src + hh * 4);
    }
    if (tid < 64) {
      const int jg = jb * 64 + tid;
      tj[tid] = t_g[jg * 64 + u];
      sj0[tid] = s_g[(jg * 64 + u) * 2 + 0];
      sj1[tid] = s_g[(jg * 64 + u) * 2 + 1];
    }
    __syncthreads();
    {
      const float tiv = ti[iloc], p0 = si0[iloc], p1 = si1[iloc];
#pragma unroll
      for (int jj = 0; jj < 16; ++jj) {
        const int j = q * 16 + jj;
        const int jgl = jb * 64 + j;
        const float dt = tiv - tj[j];
        // f_t = (cos(2*pi*dt)+1)*0.5*exp(-0.1*dt); v_cos takes revolutions
        const float ft = (__builtin_amdgcn_cosf(dt) + 1.f) * 0.5f *
                         __builtin_amdgcn_exp2f(-0.14426950408889634f * dt);
        const float dx = p0 - sj0[j], dy = p1 - sj1[j];
        const float ds = __builtin_amdgcn_sqrtf(dx * dx + dy * dy);
        const float fs = __builtin_amdgcn_exp2f(-144.26950408889634f * ds);
        float wvv = ft * fs + 1e-10f;
        if (jgl > igl) wvv = 0.f;  // causal
        w_lds[iloc][j] = wvv;
      }
    }
    __syncthreads();
    if (tid < 64) {
      float sm = 0.f;
#pragma unroll
      for (int j = 0; j < 64; ++j) sm += w_lds[tid][j];
      sum_lds[tid] += sm;
    }
    for (int j = 0; j < 64; ++j) {
      const float wvv = w_lds[iloc][j];
#pragma unroll
      for (int hh = 0; hh < 16; ++hh) {
        const f32x4 o = *(const f32x4*)&out_lds[j][q * 68 + hh * 4];
        accv[hh] += o * wvv;
      }
    }
  }
  __syncthreads();
  const float inv = 1.f / sum_lds[iloc];
  short* dst = A2 + (int64_t)((ib * 64 + iloc) * 64 + u) * 512 + q * 64;
#pragma unroll
  for (int hh = 0; hh < 16; ++hh) {
    const f32x4 v = accv[hh] * inv;
    short4 sv;
    sv.x = f2bf(v[0]); sv.y = f2bf(v[1]); sv.z = f2bf(v[2]); sv.w = f2bf(v[3]);
    *(short4*)(dst + hh * 4) = sv;
  }
}

// ---------------------------------------------------------------------------
extern "C" void kernel_launch(void* const* d_in, const int* in_sizes, int n_in,
                              void* d_out, int out_size, void* d_ws, size_t ws_size,
                              hipStream_t stream) {
  (void)in_sizes; (void)n_in; (void)out_size; (void)ws_size;
  const int*   x      = (const int*)  d_in[0];
  const float* t      = (const float*)d_in[1];
  const float* s      = (const float*)d_in[2];
  // d_in[3], d_in[4] (y_t, y_s) unused by reference
  const float* h0     = (const float*)d_in[5];
  const int*   au     = (const int*)  d_in[6];
  const float* enc_W  = (const float*)d_in[7];
  const float* user_W = (const float*)d_in[8];
  const float* W_ih   = (const float*)d_in[9];
  const float* W_hh   = (const float*)d_in[10];
  const float* b_ih   = (const float*)d_in[11];
  const float* b_hh   = (const float*)d_in[12];
  const float* fc_W   = (const float*)d_in[13];
  const float* fc_b   = (const float*)d_in[14];

  float* y = (float*)d_out;
  float* hlast = y + Y_ELEMS;

  char* ws = (char*)d_ws;
  short* giV   = (short*)(ws + 0);          // 10000x256x4 bf16, pair-packed
  short* A2    = (short*)(ws + 20480000);   // 16384x512 bf16
  short* fcWb  = (short*)(ws + 37257216);   // 10000x512 bf16
  short* encWb = (short*)(ws + 47497216);   // 10000x256 bf16
  short* WihB  = (short*)(ws + 52617216);   // 768x256 bf16
  float* gout  = (float*)(ws + 53010432);   // 256x64x256 f32 GRU hiddens
  // WhhFrag scratch lives inside d_out's y region (written by prep, read by
  // GRU, overwritten by the final GEMM) to avoid growing ws usage.
  short* WhhFrag = (short*)(y + 80000000);  // 768x256 bf16, fragment-linear

  fpp_prep<<<1024, 256, 0, stream>>>(enc_W, W_ih, fc_W, user_W, W_hh, au,
                                     encWb, WihB, fcWb, A2, WhhFrag);
  // giV = enc_W @ W_ih.T + b_ih (+ b_hh for n<512); bf16, pair-packed layout
  fpp_gemm_bt<2><<<79 * 6, 256, 0, stream>>>(encWb, WihB, giV, b_ih, b_hh, 512,
                                             10000, 768, 256, 0, 79, 6, 1);
  fpp_gru<<<8, 512, 0, stream>>>(x, h0, WhhFrag, b_hh, giV, gout, hlast);
  fpp_attn<<<dim3(64, 4), 256, 0, stream>>>(t, s, gout, A2);
  // y = A2 @ fc_W.T + fc_b ; f32 out
  fpp_gemm_bt<0><<<128 * 79, 256, 0, stream>>>(A2, fcWb, y, fc_b, nullptr, 0,
                                               16384, 10000, 512, 10000, 128, 79, 8);
}